// Round 3
// baseline (199.330 us; speedup 1.0000x reference)
//
#include <hip/hip_runtime.h>
#include <math.h>

// CTC forward loss, linear-domain alpha recursion, power-of-2 renorm.
// B=256 -> one wave per batch/CU. Lane l owns states 4l..4l+3 (+ state 256
// as slot 4 on lane 63).
//
// Round-11: R10 showed the 4-deep DS pipeline only bought 105->97 cy/step,
// so DS latency was NOT the binder. The remaining ~50cy/step stall is the
// vmcnt wait: 16 KB in flight per CU / ~3000cy loaded HBM latency = ~5 B/cy
// (Little's law), vs ~10 B/cy demand at the issue floor. Fix: widen the
// VGPR prefetch ring 16 -> 48 chunks (v32..v223, 46 KB steady in-flight).
// Banks/state relocate to v224..v255 (VGPR=256; only 1 wave/CU so free).
// DS schedule (4-step read-ahead, lgkmcnt(11), 32-row LDS ring) unchanged.
// Loop: 9 x (3-superblock body, 48 loads) + 2 superblocks (32 loads) +
// 46-pair tail (vmcnt 45..0) + 4 FN drains. 512 loads/512 writes/1024 steps.
//
// ---- register map (inside the blob) --------------------------------------
// v10 global voffset  v11 LDS write addr  v12/v13 read addr label0/label1
// v14 blank base      v15 dummy           v30:31 L=(allow1,allow3)
// v32-223  48-chunk global queue (chunk c -> slot c%48 -> v[32+4*(c%48)])
// v224-238 4 read banks: k -> {lab0 v224+4k, lab1 v225+4k, blank v226+4k}
// v240:241 P=(a0,a2)  v242:243 Q=(a1,a3)  v244 a4  v245 tmp
// v246:247 R=(x,a1dup) v248:249 CB=(cb,cb) v250:251 C13=(c1,c3)
// v252:253 EPS pair    v254:255 t-pair / renorm scratch (v255)
// s90 loop counter, s91-95 renorm scratch

#define T_DIM 1024
#define C_DIM 128
#define U_DIM 128
#define LN2F  0.6931471805599453f

#define EPS_LIT "0x33d6bf95"   /* 1e-7f */

// c-multipliers for this step, from bank regs: CB=(cb,cb), C13=(c1,c3)
#define CMT(BP,BB) \
  "v_add_f32 v248, v252, " BB "\n\t" \
  "v_mov_b32 v249, v248\n\t" \
  "v_pk_add_f32 v[250:251], " BP ", v[252:253]\n\t"

// gather reads for row t+4 into bank k (issued AFTER CMT consumed bank k)
#define RD(B0,B1,B2,ROFF,RBOFF) \
  "ds_read_b32 " B0 ", v12 offset:" ROFF "\n\t" \
  "ds_read_b32 " B1 ", v13 offset:" ROFF "\n\t" \
  "ds_read_b32 " B2 ", v14 offset:" RBOFF "\n\t"

// packed alpha step:
//  t1 = Q+P = (a1+a0, a3+a2); t2 = R*L + t1; Q' = t2*(c1,c3)
//  P' = (P+R)*(cb,cb) = ((a0+x)*cb, (a2+a1)*cb); a4' = (a3+a4)*cb
#define ALPHA \
  "v_mov_b32_dpp v246, v243 wave_shr:1 row_mask:0xf bank_mask:0xf bound_ctrl:0\n\t" \
  "v_mov_b32 v247, v242\n\t" \
  "v_pk_add_f32 v[254:255], v[242:243], v[240:241]\n\t" \
  "v_pk_fma_f32 v[254:255], v[246:247], v[30:31], v[254:255]\n\t" \
  "v_pk_add_f32 v[240:241], v[240:241], v[246:247]\n\t" \
  "v_add_f32 v245, v243, v244\n\t" \
  "v_pk_mul_f32 v[242:243], v[254:255], v[250:251]\n\t" \
  "v_pk_mul_f32 v[240:241], v[240:241], v[248:249]\n\t" \
  "v_mul_f32 v244, v245, v248\n\t"

#define RENORM \
  "v_max_f32 v255, v240, v241\n\t" \
  "v_max_f32 v255, v255, v242\n\t" \
  "v_max_f32 v255, v255, v243\n\t" \
  "v_max_f32 v255, v255, v244\n\t" \
  "s_nop 1\n\t" \
  "v_max_f32_dpp v255, v255, v255 row_ror:8 row_mask:0xf bank_mask:0xf\n\t" \
  "s_nop 1\n\t" \
  "v_max_f32_dpp v255, v255, v255 row_ror:4 row_mask:0xf bank_mask:0xf\n\t" \
  "s_nop 1\n\t" \
  "v_max_f32_dpp v255, v255, v255 row_ror:2 row_mask:0xf bank_mask:0xf\n\t" \
  "s_nop 1\n\t" \
  "v_max_f32_dpp v255, v255, v255 row_ror:1 row_mask:0xf bank_mask:0xf\n\t" \
  "s_nop 1\n\t" \
  "v_readlane_b32 s91, v255, 0\n\t" \
  "v_readlane_b32 s92, v255, 16\n\t" \
  "v_readlane_b32 s93, v255, 32\n\t" \
  "v_readlane_b32 s94, v255, 48\n\t" \
  "s_nop 1\n\t" \
  "s_max_u32 s91, s91, s92\n\t" \
  "s_max_u32 s93, s93, s94\n\t" \
  "s_max_u32 s91, s91, s93\n\t" \
  "s_lshr_b32 s92, s91, 23\n\t" \
  "s_and_b32 s92, s92, 0xff\n\t" \
  "s_sub_u32 s93, 0x126, s92\n\t" \
  "s_min_u32 s93, s93, 0xfe\n\t" \
  "s_lshl_b32 s94, s93, 23\n\t" \
  "s_sub_u32 s95, 0x7f, s93\n\t" \
  "s_add_u32 %[EA], %[EA], s95\n\t" \
  "v_mul_f32 v240, s94, v240\n\t" \
  "v_mul_f32 v241, s94, v241\n\t" \
  "v_mul_f32 v242, s94, v242\n\t" \
  "v_mul_f32 v243, s94, v243\n\t" \
  "v_mul_f32 v244, s94, v244\n\t"

// Variadic indirection so the K0..K3 bundles expand BEFORE param matching.
#define SE(...) SE_X(__VA_ARGS__)
#define SO(...) SO_X(__VA_ARGS__)
#define TE(...) TE_X(__VA_ARGS__)

// Even step (steady): wait oldest-needed chunk (48-deep ring -> vmcnt(45)),
// write chunk (rows t+4,t+5), load chunk t/2+48 into the slot freed 4 steps
// ago, commit row t (bank k), issue reads row t+4 (same bank).
#define SE_X(QW,WOFF,QL,B0,B1,B2,BP,RBOFF) \
  "s_waitcnt vmcnt(45)\n\t" \
  "ds_write_b128 v11, v[" QW "] offset:" WOFF "\n\t" \
  "global_load_dwordx4 v[" QL "], v10, %[P]\n\t" \
  "v_add_u32 v10, 0x400, v10\n\t" \
  "s_waitcnt lgkmcnt(11)\n\t" \
  CMT(BP,B2) RD(B0,B1,B2,WOFF,RBOFF) ALPHA

// Odd step: commit row t (bank k), issue reads row t+4 (same bank).
#define SO_X(B0,B1,B2,BP,ROFF,RBOFF) \
  "s_waitcnt lgkmcnt(11)\n\t" \
  CMT(BP,B2) RD(B0,B1,B2,ROFF,RBOFF) ALPHA

// Tail even step (no more global loads; descending vmcnt).
#define TE_X(VC,QW,WOFF,B0,B1,B2,BP,RBOFF) \
  "s_waitcnt vmcnt(" VC ")\n\t" \
  "ds_write_b128 v11, v[" QW "] offset:" WOFF "\n\t" \
  "s_waitcnt lgkmcnt(11)\n\t" \
  CMT(BP,B2) RD(B0,B1,B2,WOFF,RBOFF) ALPHA

// Final drain steps: no writes, no reads, descending lgkmcnt.
#define FN(LGK,BP,BB) \
  "s_waitcnt lgkmcnt(" LGK ")\n\t" \
  CMT(BP,BB) ALPHA

// bank register name bundles (k = t & 3)
#define K0 "v224","v225","v226","v[224:225]"
#define K1 "v228","v229","v230","v[228:229]"
#define K2 "v232","v233","v234","v[232:233]"
#define K3 "v236","v237","v238","v[236:237]"

// prefill one chunk
#define PF(R) \
  "global_load_dwordx4 v[" R "], v10, %[P]\n\t" \
  "v_add_u32 v10, 0x400, v10\n\t"

// One 32-step superblock. A0..A17 are ring slot reg-ranges: SE pair i uses
// QL=A(i), QW=A(i+2). LDS offsets cycle the 32-row ring exactly as before.
#define SB(A0,A1,A2,A3,A4,A5,A6,A7,A8,A9,A10,A11,A12,A13,A14,A15,A16,A17) \
  SE(A2,"2048",A0,K0,"2556")    SO(K1,"2560","3068") \
  SE(A3,"3072",A1,K2,"3580")    SO(K3,"3584","4092") \
  SE(A4,"4096",A2,K0,"4604")    SO(K1,"4608","5116") \
  SE(A5,"5120",A3,K2,"5628")    SO(K3,"5632","6140")   RENORM \
  SE(A6,"6144",A4,K0,"6652")    SO(K1,"6656","7164") \
  SE(A7,"7168",A5,K2,"7676")    SO(K3,"7680","8188") \
  SE(A8,"8192",A6,K0,"8700")    SO(K1,"8704","9212") \
  SE(A9,"9216",A7,K2,"9724")    SO(K3,"9728","10236")  RENORM \
  SE(A10,"10240",A8,K0,"10748") SO(K1,"10752","11260") \
  SE(A11,"11264",A9,K2,"11772") SO(K3,"11776","12284") \
  SE(A12,"12288",A10,K0,"12796") SO(K1,"12800","13308") \
  SE(A13,"13312",A11,K2,"13820") SO(K3,"13824","14332") RENORM \
  SE(A14,"14336",A12,K0,"14844") SO(K1,"14848","15356") \
  SE(A15,"15360",A13,K2,"15868") SO(K3,"15872","16380") \
  SE(A16,"0",A14,K0,"508")      SO(K1,"512","1020") \
  SE(A17,"1024",A15,K2,"1532")  SO(K3,"1536","2044")   RENORM

// The three superblocks of one 48-load body (slot phase advances 16/SB).
#define SB_A SB("32:35","36:39","40:43","44:47","48:51","52:55","56:59",\
"60:63","64:67","68:71","72:75","76:79","80:83","84:87","88:91","92:95",\
"96:99","100:103")
#define SB_B SB("96:99","100:103","104:107","108:111","112:115","116:119",\
"120:123","124:127","128:131","132:135","136:139","140:143","144:147",\
"148:151","152:155","156:159","160:163","164:167")
#define SB_C SB("160:163","164:167","168:171","172:175","176:179","180:183",\
"184:187","188:191","192:195","196:199","200:203","204:207","208:211",\
"212:215","216:219","220:223","32:35","36:39")

__global__ __launch_bounds__(64) void ctc_alpha_kernel(
    const int*   __restrict__ y_true,   // (B, U) int32
    const float* __restrict__ y_pred,   // (B, T, C) f32 softmax probs
    float*       __restrict__ out,      // (B, 1) f32
    int B)
{
  __shared__ float4 ldsbuf[1024];       // 16 KB: 32-row x 512 B ring

  const int b = blockIdx.x;
  if (b >= B) return;
  const int lane = threadIdx.x;           // 0..63
  const float* __restrict__ p  = y_pred + (size_t)b * (T_DIM * C_DIM);
  const int*   __restrict__ yb = y_true + b * U_DIM;
  const int blank = C_DIM - 1;

  // Labels for this lane's odd states: s=4l+1 -> u=2l ; s=4l+3 -> u=2l+1
  const int ylab0 = yb[2 * lane];
  const int ylab1 = yb[2 * lane + 1];
  int yprev = blank;
  if (lane > 0) yprev = yb[2 * lane - 1];
  const float allow1 = (lane > 0 && ylab0 != blank && ylab0 != yprev) ? 1.0f : 0.0f;
  const float allow3 = (ylab1 != blank && ylab1 != ylab0)             ? 1.0f : 0.0f;

  const unsigned lds_off = (unsigned)(uintptr_t)(void*)ldsbuf;
  const int gvoff = lane * 16;                    // global: lane slice of a 1KB chunk
  const int wraddr = (int)lds_off + lane * 16;    // LDS write addr
  const int rd1    = (int)lds_off + ylab0 * 4;    // LDS read addr, label0
  const int rd3    = (int)lds_off + ylab1 * 4;    // LDS read addr, label1
  const int rdb    = (int)lds_off;                // blank via offset imm +508

  // Virtual init: alpha_{-1}=1 on lane0 makes t=0 a uniform step.
  const float init0 = (lane == 0) ? 1.0f : 0.0f;
  float a3out, a4out;
  int   e_acc = 0;

  asm volatile(
    // ---- prologue ------------------------------------------------------
    "s_mov_b32 m0, -1\n\t"
    "v_mov_b32 v10, %[GV]\n\t"
    "v_mov_b32 v11, %[WA]\n\t"
    "v_mov_b32 v12, %[R1]\n\t"
    "v_mov_b32 v13, %[R3]\n\t"
    "v_mov_b32 v14, %[RB]\n\t"
    "v_mov_b32 v30, %[L1]\n\t"
    "v_mov_b32 v31, %[L3]\n\t"
    "v_mov_b32 v240, %[I0]\n\t"
    "v_mov_b32 v241, 0\n\t"
    "v_mov_b32 v242, 0\n\t"
    "v_mov_b32 v243, 0\n\t"
    "v_mov_b32 v244, 0\n\t"
    "v_mov_b32 v252, " EPS_LIT "\n\t"
    "v_mov_b32 v253, " EPS_LIT "\n\t"
    // prefill 48 chunks (rows 0..95)
    PF("32:35")   PF("36:39")   PF("40:43")   PF("44:47")
    PF("48:51")   PF("52:55")   PF("56:59")   PF("60:63")
    PF("64:67")   PF("68:71")   PF("72:75")   PF("76:79")
    PF("80:83")   PF("84:87")   PF("88:91")   PF("92:95")
    PF("96:99")   PF("100:103") PF("104:107") PF("108:111")
    PF("112:115") PF("116:119") PF("120:123") PF("124:127")
    PF("128:131") PF("132:135") PF("136:139") PF("140:143")
    PF("144:147") PF("148:151") PF("152:155") PF("156:159")
    PF("160:163") PF("164:167") PF("168:171") PF("172:175")
    PF("176:179") PF("180:183") PF("184:187") PF("188:191")
    PF("192:195") PF("196:199") PF("200:203") PF("204:207")
    PF("208:211") PF("212:215") PF("216:219") PF("220:223")
    // chunks 0,1 -> LDS rows 0..3; prime gathers for rows 0..3 (banks 0..3).
    // Two dummy reads pad the in-order DS queue so the steady lgkmcnt(11)
    // wait fully drains rows 0/1 at steps t=0,1.
    "s_waitcnt vmcnt(47)\n\t"
    "ds_write_b128 v11, v[32:35] offset:0\n\t"
    "s_waitcnt vmcnt(46)\n\t"
    "ds_write_b128 v11, v[36:39] offset:1024\n\t"
    "ds_read_b32 v224, v12 offset:0\n\t"
    "ds_read_b32 v225, v13 offset:0\n\t"
    "ds_read_b32 v226, v14 offset:508\n\t"
    "ds_read_b32 v15, v14 offset:508\n\t"          // dummy
    "ds_read_b32 v228, v12 offset:512\n\t"
    "ds_read_b32 v229, v13 offset:512\n\t"
    "ds_read_b32 v230, v14 offset:1020\n\t"
    "ds_read_b32 v15, v14 offset:508\n\t"          // dummy
    "ds_read_b32 v232, v12 offset:1024\n\t"
    "ds_read_b32 v233, v13 offset:1024\n\t"
    "ds_read_b32 v234, v14 offset:1532\n\t"
    "ds_read_b32 v236, v12 offset:1536\n\t"
    "ds_read_b32 v237, v13 offset:1536\n\t"
    "ds_read_b32 v238, v14 offset:2044\n\t"
    // ---- main loop: 9 x 96 steps = steps 0..863 ------------------------
    "s_mov_b32 s90, 9\n"
    "LM_%=:\n\t"
    SB_A SB_B SB_C
    "s_sub_u32 s90, s90, 1\n\t"
    "s_cmp_lg_u32 s90, 0\n\t"
    "s_cbranch_scc1 LM_%=\n\t"
    // ---- partial group: steps 864..927 (last 32 loads) -----------------
    SB_A SB_B
    // ---- tail: steps 928..1019 (no more global loads) ------------------
    TE("45","168:171","2048",K0,"2556")   SO(K1,"2560","3068")
    TE("44","172:175","3072",K2,"3580")   SO(K3,"3584","4092")
    TE("43","176:179","4096",K0,"4604")   SO(K1,"4608","5116")
    TE("42","180:183","5120",K2,"5628")   SO(K3,"5632","6140")   RENORM
    TE("41","184:187","6144",K0,"6652")   SO(K1,"6656","7164")
    TE("40","188:191","7168",K2,"7676")   SO(K3,"7680","8188")
    TE("39","192:195","8192",K0,"8700")   SO(K1,"8704","9212")
    TE("38","196:199","9216",K2,"9724")   SO(K3,"9728","10236")  RENORM
    TE("37","200:203","10240",K0,"10748") SO(K1,"10752","11260")
    TE("36","204:207","11264",K2,"11772") SO(K3,"11776","12284")
    TE("35","208:211","12288",K0,"12796") SO(K1,"12800","13308")
    TE("34","212:215","13312",K2,"13820") SO(K3,"13824","14332") RENORM
    TE("33","216:219","14336",K0,"14844") SO(K1,"14848","15356")
    TE("32","220:223","15360",K2,"15868") SO(K3,"15872","16380")
    TE("31","32:35","0",K0,"508")         SO(K1,"512","1020")
    TE("30","36:39","1024",K2,"1532")     SO(K3,"1536","2044")   RENORM
    TE("29","40:43","2048",K0,"2556")     SO(K1,"2560","3068")
    TE("28","44:47","3072",K2,"3580")     SO(K3,"3584","4092")
    TE("27","48:51","4096",K0,"4604")     SO(K1,"4608","5116")
    TE("26","52:55","5120",K2,"5628")     SO(K3,"5632","6140")   RENORM
    TE("25","56:59","6144",K0,"6652")     SO(K1,"6656","7164")
    TE("24","60:63","7168",K2,"7676")     SO(K3,"7680","8188")
    TE("23","64:67","8192",K0,"8700")     SO(K1,"8704","9212")
    TE("22","68:71","9216",K2,"9724")     SO(K3,"9728","10236")  RENORM
    TE("21","72:75","10240",K0,"10748")   SO(K1,"10752","11260")
    TE("20","76:79","11264",K2,"11772")   SO(K3,"11776","12284")
    TE("19","80:83","12288",K0,"12796")   SO(K1,"12800","13308")
    TE("18","84:87","13312",K2,"13820")   SO(K3,"13824","14332") RENORM
    TE("17","88:91","14336",K0,"14844")   SO(K1,"14848","15356")
    TE("16","92:95","15360",K2,"15868")   SO(K3,"15872","16380")
    TE("15","96:99","0",K0,"508")         SO(K1,"512","1020")
    TE("14","100:103","1024",K2,"1532")   SO(K3,"1536","2044")   RENORM
    TE("13","104:107","2048",K0,"2556")   SO(K1,"2560","3068")
    TE("12","108:111","3072",K2,"3580")   SO(K3,"3584","4092")
    TE("11","112:115","4096",K0,"4604")   SO(K1,"4608","5116")
    TE("10","116:119","5120",K2,"5628")   SO(K3,"5632","6140")   RENORM
    TE("9","120:123","6144",K0,"6652")    SO(K1,"6656","7164")
    TE("8","124:127","7168",K2,"7676")    SO(K3,"7680","8188")
    TE("7","128:131","8192",K0,"8700")    SO(K1,"8704","9212")
    TE("6","132:135","9216",K2,"9724")    SO(K3,"9728","10236")  RENORM
    TE("5","136:139","10240",K0,"10748")  SO(K1,"10752","11260")
    TE("4","140:143","11264",K2,"11772")  SO(K3,"11776","12284")
    TE("3","144:147","12288",K0,"12796")  SO(K1,"12800","13308")
    TE("2","148:151","13312",K2,"13820")  SO(K3,"13824","14332") RENORM
    TE("1","152:155","14336",K0,"14844")  SO(K1,"14848","15356")
    TE("0","156:159","15360",K2,"15868")  SO(K3,"15872","16380")
    // steps 1020..1023: pure compute, drain the DS queue
    FN("10","v[224:225]","v226")
    FN("7","v[228:229]","v230")
    FN("3","v[232:233]","v234")
    FN("0","v[236:237]","v238")
    RENORM
    // ---- epilogue: move results out ------------------------------------
    "v_mov_b32 %[O3], v243\n\t"
    "v_mov_b32 %[O4], v244\n\t"
    : [O3]"=v"(a3out), [O4]"=v"(a4out), [EA]"+s"(e_acc)
    : [P]"s"(p), [GV]"v"(gvoff), [WA]"v"(wraddr), [R1]"v"(rd1), [R3]"v"(rd3),
      [RB]"v"(rdb), [L1]"v"(allow1), [L3]"v"(allow3), [I0]"v"(init0)
    : "v10","v11","v12","v13","v14","v15","v30","v31",
      "v32","v33","v34","v35","v36","v37","v38","v39","v40","v41","v42","v43",
      "v44","v45","v46","v47","v48","v49","v50","v51","v52","v53","v54","v55",
      "v56","v57","v58","v59","v60","v61","v62","v63","v64","v65","v66","v67",
      "v68","v69","v70","v71","v72","v73","v74","v75","v76","v77","v78","v79",
      "v80","v81","v82","v83","v84","v85","v86","v87","v88","v89","v90","v91",
      "v92","v93","v94","v95","v96","v97","v98","v99","v100","v101","v102",
      "v103","v104","v105","v106","v107","v108","v109","v110","v111","v112",
      "v113","v114","v115","v116","v117","v118","v119","v120","v121","v122",
      "v123","v124","v125","v126","v127","v128","v129","v130","v131","v132",
      "v133","v134","v135","v136","v137","v138","v139","v140","v141","v142",
      "v143","v144","v145","v146","v147","v148","v149","v150","v151","v152",
      "v153","v154","v155","v156","v157","v158","v159","v160","v161","v162",
      "v163","v164","v165","v166","v167","v168","v169","v170","v171","v172",
      "v173","v174","v175","v176","v177","v178","v179","v180","v181","v182",
      "v183","v184","v185","v186","v187","v188","v189","v190","v191","v192",
      "v193","v194","v195","v196","v197","v198","v199","v200","v201","v202",
      "v203","v204","v205","v206","v207","v208","v209","v210","v211","v212",
      "v213","v214","v215","v216","v217","v218","v219","v220","v221","v222",
      "v223","v224","v225","v226","v227","v228","v229","v230","v231","v232",
      "v233","v234","v235","v236","v237","v238","v239","v240","v241","v242",
      "v243","v244","v245","v246","v247","v248","v249","v250","v251","v252",
      "v253","v254","v255",
      "s90","s91","s92","s93","s94","s95","scc","memory");

  if (lane == 63) {
    float s = a3out + a4out;           // alpha[255] + alpha[256]
    s = fmaxf(s, 1e-37f);
    float ll = logf(s) + (float)e_acc * LN2F;
    out[b] = -ll;
  }
}

extern "C" void kernel_launch(void* const* d_in, const int* in_sizes, int n_in,
                              void* d_out, int out_size, void* d_ws, size_t ws_size,
                              hipStream_t stream) {
  const int*   y_true = (const int*)d_in[0];
  const float* y_pred = (const float*)d_in[1];
  float*       out    = (float*)d_out;
  const int B = in_sizes[0] / U_DIM;   // 256
  ctc_alpha_kernel<<<dim3(B), dim3(64), 0, stream>>>(y_true, y_pred, out, B);
}

// Round 4
// 196.524 us; speedup vs baseline: 1.0143x; 1.0143x over previous
//
#include <hip/hip_runtime.h>
#include <math.h>

// CTC forward loss, linear-domain alpha recursion, power-of-2 renorm.
// B=256 -> one wave per batch/CU. Lane l owns states 4l..4l+3 (+ state 256
// as slot 4 on lane 63).
//
// Round-12: R10 (4-deep DS pipe) and R11 (48-chunk HBM ring) both nulled ->
// kernel is execute-bound on the single wave, not wait-bound. This round:
// revert to the R10 16-chunk ring (smaller code, R10 > R11), and DELETE the
// blank gather: cb = p[row][127] already lives in the chunk regs (row 2c:
// lane 31 comp 3; row 2c+1: lane 63 comp 3). Two v_readlane per SE stage it
// into an 8-slot rotating SGPR file (s80+row%8), written 4-5 steps before
// use. CMT's cb add now reads an SGPR (ready instantly post-wait). Steps
// drop to 2 ds_reads; uniform s_waitcnt lgkmcnt(8) (queue re-derived:
// SE kept = w(t)+2r(t-1)+[w+2r](t-2)+2r(t-3) = 8; SO same by parity).
// Prologue pads: r0,d0,r1,d1,r2,r3. FN drains 7/5/2/0.
//
// ---- register map (inside the blob) --------------------------------------
// v10 global voffset  v11 LDS write addr  v12/v13 read addr label0/label1
// v14 dummy-read addr v15 dummy dst       v30:31 L=(allow1,allow3)
// v32-95  16-chunk global queue (chunk c -> v[32+4*(c&15)])
// v96-109 4 read banks: k=t&3 -> {lab0 v96+4k, lab1 v97+4k}
// v112:113 P=(a0,a2)  v114:115 Q=(a1,a3)  v116 a4  v117 tmp
// v118:119 R=(x,a1dup) v120:121 CB=(cb,cb) v122:123 C13=(c1,c3)
// v124:125 EPS pair    v126:127 t-pair / renorm scratch (v127)
// s80-87 cb ring (slot = row mod 8)  s90 loop counter  s91-95 renorm scratch

#define T_DIM 1024
#define C_DIM 128
#define U_DIM 128
#define LN2F  0.6931471805599453f

#define EPS_LIT "0x33d6bf95"   /* 1e-7f */

// c-multipliers for this step. cb from the SGPR ring (staged by readlane),
// (c1,c3) from bank regs BP.
#define CMT(BP,CB) \
  "v_add_f32 v120, " CB ", v124\n\t" \
  "v_mov_b32 v121, v120\n\t" \
  "v_pk_add_f32 v[122:123], " BP ", v[124:125]\n\t"

// gather reads for row t+4 into bank k (issued AFTER CMT consumed bank k)
#define RD2(B0,B1,ROFF) \
  "ds_read_b32 " B0 ", v12 offset:" ROFF "\n\t" \
  "ds_read_b32 " B1 ", v13 offset:" ROFF "\n\t"

// packed alpha step:
//  t1 = Q+P = (a1+a0, a3+a2); t2 = R*L + t1; Q' = t2*(c1,c3)
//  P' = (P+R)*(cb,cb) = ((a0+x)*cb, (a2+a1)*cb); a4' = (a3+a4)*cb
#define ALPHA \
  "v_mov_b32_dpp v118, v115 wave_shr:1 row_mask:0xf bank_mask:0xf bound_ctrl:0\n\t" \
  "v_mov_b32 v119, v114\n\t" \
  "v_pk_add_f32 v[126:127], v[114:115], v[112:113]\n\t" \
  "v_pk_fma_f32 v[126:127], v[118:119], v[30:31], v[126:127]\n\t" \
  "v_pk_add_f32 v[112:113], v[112:113], v[118:119]\n\t" \
  "v_add_f32 v117, v115, v116\n\t" \
  "v_pk_mul_f32 v[114:115], v[126:127], v[122:123]\n\t" \
  "v_pk_mul_f32 v[112:113], v[112:113], v[120:121]\n\t" \
  "v_mul_f32 v116, v117, v120\n\t"

#define RENORM \
  "v_max_f32 v127, v112, v113\n\t" \
  "v_max_f32 v127, v127, v114\n\t" \
  "v_max_f32 v127, v127, v115\n\t" \
  "v_max_f32 v127, v127, v116\n\t" \
  "s_nop 1\n\t" \
  "v_max_f32_dpp v127, v127, v127 row_ror:8 row_mask:0xf bank_mask:0xf\n\t" \
  "s_nop 1\n\t" \
  "v_max_f32_dpp v127, v127, v127 row_ror:4 row_mask:0xf bank_mask:0xf\n\t" \
  "s_nop 1\n\t" \
  "v_max_f32_dpp v127, v127, v127 row_ror:2 row_mask:0xf bank_mask:0xf\n\t" \
  "s_nop 1\n\t" \
  "v_max_f32_dpp v127, v127, v127 row_ror:1 row_mask:0xf bank_mask:0xf\n\t" \
  "s_nop 1\n\t" \
  "v_readlane_b32 s91, v127, 0\n\t" \
  "v_readlane_b32 s92, v127, 16\n\t" \
  "v_readlane_b32 s93, v127, 32\n\t" \
  "v_readlane_b32 s94, v127, 48\n\t" \
  "s_nop 1\n\t" \
  "s_max_u32 s91, s91, s92\n\t" \
  "s_max_u32 s93, s93, s94\n\t" \
  "s_max_u32 s91, s91, s93\n\t" \
  "s_lshr_b32 s92, s91, 23\n\t" \
  "s_and_b32 s92, s92, 0xff\n\t" \
  "s_sub_u32 s93, 0x126, s92\n\t" \
  "s_min_u32 s93, s93, 0xfe\n\t" \
  "s_lshl_b32 s94, s93, 23\n\t" \
  "s_sub_u32 s95, 0x7f, s93\n\t" \
  "s_add_u32 %[EA], %[EA], s95\n\t" \
  "v_mul_f32 v112, s94, v112\n\t" \
  "v_mul_f32 v113, s94, v113\n\t" \
  "v_mul_f32 v114, s94, v114\n\t" \
  "v_mul_f32 v115, s94, v115\n\t" \
  "v_mul_f32 v116, s94, v116\n\t"

// Variadic indirection so the K0..K7 bundles expand BEFORE param matching.
#define SE(...) SE_X(__VA_ARGS__)
#define SO(...) SO_X(__VA_ARGS__)
#define TE(...) TE_X(__VA_ARGS__)

// Even step (steady): wait chunk (vmcnt 13), write rows t+4/t+5 to LDS,
// load chunk t/2+16, readlane the two blank probs into the SGPR ring
// (slots (t+4)&7,(t+5)&7), commit row t (bank k, cb slot t&7), issue
// gathers for row t+4.
#define SE_X(QW,Q3,WOFF,QL,SA,SB_,B0,B1,BP,CB) \
  "s_waitcnt vmcnt(13)\n\t" \
  "ds_write_b128 v11, v[" QW "] offset:" WOFF "\n\t" \
  "global_load_dwordx4 v[" QL "], v10, %[P]\n\t" \
  "v_add_u32 v10, 0x400, v10\n\t" \
  "v_readlane_b32 " SA ", v" Q3 ", 31\n\t" \
  "v_readlane_b32 " SB_ ", v" Q3 ", 63\n\t" \
  "s_waitcnt lgkmcnt(8)\n\t" \
  CMT(BP,CB) RD2(B0,B1,WOFF) ALPHA

// Odd step: commit row t (bank k), issue gathers for row t+4.
#define SO_X(B0,B1,BP,CB,ROFF) \
  "s_waitcnt lgkmcnt(8)\n\t" \
  CMT(BP,CB) RD2(B0,B1,ROFF) ALPHA

// Tail even step (no more global loads; descending vmcnt).
#define TE_X(VC,QW,Q3,WOFF,SA,SB_,B0,B1,BP,CB) \
  "s_waitcnt vmcnt(" VC ")\n\t" \
  "ds_write_b128 v11, v[" QW "] offset:" WOFF "\n\t" \
  "v_readlane_b32 " SA ", v" Q3 ", 31\n\t" \
  "v_readlane_b32 " SB_ ", v" Q3 ", 63\n\t" \
  "s_waitcnt lgkmcnt(8)\n\t" \
  CMT(BP,CB) RD2(B0,B1,WOFF) ALPHA

// Final drain steps: no writes, no reads, descending lgkmcnt.
#define FN(LGK,BP,CB) \
  "s_waitcnt lgkmcnt(" LGK ")\n\t" \
  CMT(BP,CB) ALPHA

// bundles for step u: bank k=u&3 (B0,B1,BP), cb slot u&7 (CB)
#define K0 "v96","v97","v[96:97]","s80"
#define K1 "v100","v101","v[100:101]","s81"
#define K2 "v104","v105","v[104:105]","s82"
#define K3 "v108","v109","v[108:109]","s83"
#define K4 "v96","v97","v[96:97]","s84"
#define K5 "v100","v101","v[100:101]","s85"
#define K6 "v104","v105","v[104:105]","s86"
#define K7 "v108","v109","v[108:109]","s87"

__global__ __launch_bounds__(64) void ctc_alpha_kernel(
    const int*   __restrict__ y_true,   // (B, U) int32
    const float* __restrict__ y_pred,   // (B, T, C) f32 softmax probs
    float*       __restrict__ out,      // (B, 1) f32
    int B)
{
  __shared__ float4 ldsbuf[1024];       // 16 KB: 32-row x 512 B ring

  const int b = blockIdx.x;
  if (b >= B) return;
  const int lane = threadIdx.x;           // 0..63
  const float* __restrict__ p  = y_pred + (size_t)b * (T_DIM * C_DIM);
  const int*   __restrict__ yb = y_true + b * U_DIM;
  const int blank = C_DIM - 1;

  // Labels for this lane's odd states: s=4l+1 -> u=2l ; s=4l+3 -> u=2l+1
  const int ylab0 = yb[2 * lane];
  const int ylab1 = yb[2 * lane + 1];
  int yprev = blank;
  if (lane > 0) yprev = yb[2 * lane - 1];
  const float allow1 = (lane > 0 && ylab0 != blank && ylab0 != yprev) ? 1.0f : 0.0f;
  const float allow3 = (ylab1 != blank && ylab1 != ylab0)             ? 1.0f : 0.0f;

  const unsigned lds_off = (unsigned)(uintptr_t)(void*)ldsbuf;
  const int gvoff = lane * 16;                    // global: lane slice of a 1KB chunk
  const int wraddr = (int)lds_off + lane * 16;    // LDS write addr
  const int rd1    = (int)lds_off + ylab0 * 4;    // LDS read addr, label0
  const int rd3    = (int)lds_off + ylab1 * 4;    // LDS read addr, label1
  const int rdb    = (int)lds_off;                // dummy-read base

  // Virtual init: alpha_{-1}=1 on lane0 makes t=0 a uniform step.
  const float init0 = (lane == 0) ? 1.0f : 0.0f;
  float a3out, a4out;
  int   e_acc = 0;

  asm volatile(
    // ---- prologue ------------------------------------------------------
    "s_mov_b32 m0, -1\n\t"
    "v_mov_b32 v10, %[GV]\n\t"
    "v_mov_b32 v11, %[WA]\n\t"
    "v_mov_b32 v12, %[R1]\n\t"
    "v_mov_b32 v13, %[R3]\n\t"
    "v_mov_b32 v14, %[RB]\n\t"
    "v_mov_b32 v30, %[L1]\n\t"
    "v_mov_b32 v31, %[L3]\n\t"
    "v_mov_b32 v112, %[I0]\n\t"
    "v_mov_b32 v113, 0\n\t"
    "v_mov_b32 v114, 0\n\t"
    "v_mov_b32 v115, 0\n\t"
    "v_mov_b32 v116, 0\n\t"
    "v_mov_b32 v124, " EPS_LIT "\n\t"
    "v_mov_b32 v125, " EPS_LIT "\n\t"
    // prefill 16 chunks (rows 0..31)
    "global_load_dwordx4 v[32:35], v10, %[P]\n\t" "v_add_u32 v10, 0x400, v10\n\t"
    "global_load_dwordx4 v[36:39], v10, %[P]\n\t" "v_add_u32 v10, 0x400, v10\n\t"
    "global_load_dwordx4 v[40:43], v10, %[P]\n\t" "v_add_u32 v10, 0x400, v10\n\t"
    "global_load_dwordx4 v[44:47], v10, %[P]\n\t" "v_add_u32 v10, 0x400, v10\n\t"
    "global_load_dwordx4 v[48:51], v10, %[P]\n\t" "v_add_u32 v10, 0x400, v10\n\t"
    "global_load_dwordx4 v[52:55], v10, %[P]\n\t" "v_add_u32 v10, 0x400, v10\n\t"
    "global_load_dwordx4 v[56:59], v10, %[P]\n\t" "v_add_u32 v10, 0x400, v10\n\t"
    "global_load_dwordx4 v[60:63], v10, %[P]\n\t" "v_add_u32 v10, 0x400, v10\n\t"
    "global_load_dwordx4 v[64:67], v10, %[P]\n\t" "v_add_u32 v10, 0x400, v10\n\t"
    "global_load_dwordx4 v[68:71], v10, %[P]\n\t" "v_add_u32 v10, 0x400, v10\n\t"
    "global_load_dwordx4 v[72:75], v10, %[P]\n\t" "v_add_u32 v10, 0x400, v10\n\t"
    "global_load_dwordx4 v[76:79], v10, %[P]\n\t" "v_add_u32 v10, 0x400, v10\n\t"
    "global_load_dwordx4 v[80:83], v10, %[P]\n\t" "v_add_u32 v10, 0x400, v10\n\t"
    "global_load_dwordx4 v[84:87], v10, %[P]\n\t" "v_add_u32 v10, 0x400, v10\n\t"
    "global_load_dwordx4 v[88:91], v10, %[P]\n\t" "v_add_u32 v10, 0x400, v10\n\t"
    "global_load_dwordx4 v[92:95], v10, %[P]\n\t" "v_add_u32 v10, 0x400, v10\n\t"
    // chunks 0,1 -> LDS rows 0..3; cb slots 0..3; prime gathers rows 0..3.
    // Dummies after r0 and r1 pad the in-order DS queue so lgkmcnt(8)
    // fully drains rows 0/1 at steps 0/1.
    "s_waitcnt vmcnt(15)\n\t"
    "ds_write_b128 v11, v[32:35] offset:0\n\t"
    "v_readlane_b32 s80, v35, 31\n\t"
    "v_readlane_b32 s81, v35, 63\n\t"
    "s_waitcnt vmcnt(14)\n\t"
    "ds_write_b128 v11, v[36:39] offset:1024\n\t"
    "v_readlane_b32 s82, v39, 31\n\t"
    "v_readlane_b32 s83, v39, 63\n\t"
    "ds_read_b32 v96, v12 offset:0\n\t"
    "ds_read_b32 v97, v13 offset:0\n\t"
    "ds_read_b32 v15, v14 offset:508\n\t"          // dummy d0
    "ds_read_b32 v100, v12 offset:512\n\t"
    "ds_read_b32 v101, v13 offset:512\n\t"
    "ds_read_b32 v15, v14 offset:508\n\t"          // dummy d1
    "ds_read_b32 v104, v12 offset:1024\n\t"
    "ds_read_b32 v105, v13 offset:1024\n\t"
    "ds_read_b32 v108, v12 offset:1536\n\t"
    "ds_read_b32 v109, v13 offset:1536\n\t"
    // ---- main loop: 31 superblocks x 32 steps = steps 0..991 ----------
    "s_mov_b32 s90, 31\n"
    "LM_%=:\n\t"
    SE("40:43","43","2048","32:35","s84","s85",K0)   SO(K1,"2560")
    SE("44:47","47","3072","36:39","s86","s87",K2)   SO(K3,"3584")
    SE("48:51","51","4096","40:43","s80","s81",K4)   SO(K5,"4608")
    SE("52:55","55","5120","44:47","s82","s83",K6)   SO(K7,"5632")   RENORM
    SE("56:59","59","6144","48:51","s84","s85",K0)   SO(K1,"6656")
    SE("60:63","63","7168","52:55","s86","s87",K2)   SO(K3,"7680")
    SE("64:67","67","8192","56:59","s80","s81",K4)   SO(K5,"8704")
    SE("68:71","71","9216","60:63","s82","s83",K6)   SO(K7,"9728")   RENORM
    SE("72:75","75","10240","64:67","s84","s85",K0)  SO(K1,"10752")
    SE("76:79","79","11264","68:71","s86","s87",K2)  SO(K3,"11776")
    SE("80:83","83","12288","72:75","s80","s81",K4)  SO(K5,"12800")
    SE("84:87","87","13312","76:79","s82","s83",K6)  SO(K7,"13824")  RENORM
    SE("88:91","91","14336","80:83","s84","s85",K0)  SO(K1,"14848")
    SE("92:95","95","15360","84:87","s86","s87",K2)  SO(K3,"15872")
    SE("32:35","35","0","88:91","s80","s81",K4)      SO(K5,"512")
    SE("36:39","39","1024","92:95","s82","s83",K6)   SO(K7,"1536")   RENORM
    "s_sub_u32 s90, s90, 1\n\t"
    "s_cmp_lg_u32 s90, 0\n\t"
    "s_cbranch_scc1 LM_%=\n\t"
    // ---- tail: steps 992..1019 (no more global loads) ------------------
    TE("13","40:43","43","2048","s84","s85",K0)   SO(K1,"2560")
    TE("12","44:47","47","3072","s86","s87",K2)   SO(K3,"3584")
    TE("11","48:51","51","4096","s80","s81",K4)   SO(K5,"4608")
    TE("10","52:55","55","5120","s82","s83",K6)   SO(K7,"5632")   RENORM
    TE("9","56:59","59","6144","s84","s85",K0)    SO(K1,"6656")
    TE("8","60:63","63","7168","s86","s87",K2)    SO(K3,"7680")
    TE("7","64:67","67","8192","s80","s81",K4)    SO(K5,"8704")
    TE("6","68:71","71","9216","s82","s83",K6)    SO(K7,"9728")    RENORM
    TE("5","72:75","75","10240","s84","s85",K0)   SO(K1,"10752")
    TE("4","76:79","79","11264","s86","s87",K2)   SO(K3,"11776")
    TE("3","80:83","83","12288","s80","s81",K4)   SO(K5,"12800")
    TE("2","84:87","87","13312","s82","s83",K6)   SO(K7,"13824")   RENORM
    TE("1","88:91","91","14336","s84","s85",K0)   SO(K1,"14848")
    TE("0","92:95","95","15360","s86","s87",K2)   SO(K3,"15872")
    // steps 1020..1023: pure compute, drain the DS queue
    FN("7","v[96:97]","s84")
    FN("5","v[100:101]","s85")
    FN("2","v[104:105]","s86")
    FN("0","v[108:109]","s87")
    RENORM
    // ---- epilogue: move results out ------------------------------------
    "v_mov_b32 %[O3], v115\n\t"
    "v_mov_b32 %[O4], v116\n\t"
    : [O3]"=v"(a3out), [O4]"=v"(a4out), [EA]"+s"(e_acc)
    : [P]"s"(p), [GV]"v"(gvoff), [WA]"v"(wraddr), [R1]"v"(rd1), [R3]"v"(rd3),
      [RB]"v"(rdb), [L1]"v"(allow1), [L3]"v"(allow3), [I0]"v"(init0)
    : "v10","v11","v12","v13","v14","v15","v30","v31",
      "v32","v33","v34","v35","v36","v37","v38","v39","v40","v41","v42","v43",
      "v44","v45","v46","v47","v48","v49","v50","v51","v52","v53","v54","v55",
      "v56","v57","v58","v59","v60","v61","v62","v63","v64","v65","v66","v67",
      "v68","v69","v70","v71","v72","v73","v74","v75","v76","v77","v78","v79",
      "v80","v81","v82","v83","v84","v85","v86","v87","v88","v89","v90","v91",
      "v92","v93","v94","v95","v96","v97","v98","v99","v100","v101","v102",
      "v103","v104","v105","v106","v107","v108","v109","v110","v111","v112",
      "v113","v114","v115","v116","v117","v118","v119","v120","v121","v122",
      "v123","v124","v125","v126","v127",
      "s80","s81","s82","s83","s84","s85","s86","s87",
      "s90","s91","s92","s93","s94","s95","scc","memory");

  if (lane == 63) {
    float s = a3out + a4out;           // alpha[255] + alpha[256]
    s = fmaxf(s, 1e-37f);
    float ll = logf(s) + (float)e_acc * LN2F;
    out[b] = -ll;
  }
}

extern "C" void kernel_launch(void* const* d_in, const int* in_sizes, int n_in,
                              void* d_out, int out_size, void* d_ws, size_t ws_size,
                              hipStream_t stream) {
  const int*   y_true = (const int*)d_in[0];
  const float* y_pred = (const float*)d_in[1];
  float*       out    = (float*)d_out;
  const int B = in_sizes[0] / U_DIM;   // 256
  ctc_alpha_kernel<<<dim3(B), dim3(64), 0, stream>>>(y_true, y_pred, out, B);
}

// Round 5
// 194.878 us; speedup vs baseline: 1.0228x; 1.0084x over previous
//
#include <hip/hip_runtime.h>
#include <math.h>

// CTC forward loss, linear-domain alpha recursion, power-of-2 renorm.
// B=256 -> one block per batch. Round-13: producer/consumer wave split.
// Wave 1 (producer): global->LDS staging only. 16-chunk VGPR ring, uniform
//   vmcnt(15) waits, ds_write_b128, lgkmcnt(0) before each barrier.
// Wave 0 (consumer): recursion only. 3 gather ds_read/step (lab0, lab1,
//   blank), uniform lgkmcnt(9) (own queue = reads only), CMT+ALPHA pk-f32,
//   RENORM every 8 steps. No staging in its instruction stream.
// Sync: s_barrier per 8-row group; producer 2 groups ahead on the 32-row
// (4-group) LDS ring. Producer writes slot (g+2)&3 while consumer touches
// slots (g-1..g+1)&3 -> disjoint. Barrier counts: P0 + 128 on both waves.
//
// consumer regs: v12/13 gather addrs, v14 row base, v30:31 allow pair,
//   v96-110 four 3-reg banks (c1,c3,cb; k=t&3), v112-127 alpha state
//   (P=v112:113, Q=v114:115, a4=v116, R=v118:119, CB=v120:121,
//    C13=v122:123, EPS=v124:125, t=v126:127), s90-95 scratch.
// producer regs: v10 global voffset, v11 LDS write addr, v32-95 ring.

#define T_DIM 1024
#define C_DIM 128
#define U_DIM 128
#define LN2F  0.6931471805599453f

#define EPS_LIT "0x33d6bf95"   /* 1e-7f */

// c-multipliers: cb from bank's 3rd reg (VGPR), (c1,c3) from bank pair.
#define CMT(BP,BB) \
  "v_add_f32 v120, v124, " BB "\n\t" \
  "v_mov_b32 v121, v120\n\t" \
  "v_pk_add_f32 v[122:123], " BP ", v[124:125]\n\t"

// packed alpha step (IEEE-identical to R10/R12):
//  t1 = Q+P; t2 = R*L + t1; Q' = t2*(c1,c3)
//  P' = (P+R)*cb ; a4' = (a3+a4)*cb
#define ALPHA \
  "v_mov_b32_dpp v118, v115 wave_shr:1 row_mask:0xf bank_mask:0xf bound_ctrl:0\n\t" \
  "v_mov_b32 v119, v114\n\t" \
  "v_pk_add_f32 v[126:127], v[114:115], v[112:113]\n\t" \
  "v_pk_fma_f32 v[126:127], v[118:119], v[30:31], v[126:127]\n\t" \
  "v_pk_add_f32 v[112:113], v[112:113], v[118:119]\n\t" \
  "v_add_f32 v117, v115, v116\n\t" \
  "v_pk_mul_f32 v[114:115], v[126:127], v[122:123]\n\t" \
  "v_pk_mul_f32 v[112:113], v[112:113], v[120:121]\n\t" \
  "v_mul_f32 v116, v117, v120\n\t"

#define RENORM \
  "v_max_f32 v127, v112, v113\n\t" \
  "v_max_f32 v127, v127, v114\n\t" \
  "v_max_f32 v127, v127, v115\n\t" \
  "v_max_f32 v127, v127, v116\n\t" \
  "s_nop 1\n\t" \
  "v_max_f32_dpp v127, v127, v127 row_ror:8 row_mask:0xf bank_mask:0xf\n\t" \
  "s_nop 1\n\t" \
  "v_max_f32_dpp v127, v127, v127 row_ror:4 row_mask:0xf bank_mask:0xf\n\t" \
  "s_nop 1\n\t" \
  "v_max_f32_dpp v127, v127, v127 row_ror:2 row_mask:0xf bank_mask:0xf\n\t" \
  "s_nop 1\n\t" \
  "v_max_f32_dpp v127, v127, v127 row_ror:1 row_mask:0xf bank_mask:0xf\n\t" \
  "s_nop 1\n\t" \
  "v_readlane_b32 s91, v127, 0\n\t" \
  "v_readlane_b32 s92, v127, 16\n\t" \
  "v_readlane_b32 s93, v127, 32\n\t" \
  "v_readlane_b32 s94, v127, 48\n\t" \
  "s_nop 1\n\t" \
  "s_max_u32 s91, s91, s92\n\t" \
  "s_max_u32 s93, s93, s94\n\t" \
  "s_max_u32 s91, s91, s93\n\t" \
  "s_lshr_b32 s92, s91, 23\n\t" \
  "s_and_b32 s92, s92, 0xff\n\t" \
  "s_sub_u32 s93, 0x126, s92\n\t" \
  "s_min_u32 s93, s93, 0xfe\n\t" \
  "s_lshl_b32 s94, s93, 23\n\t" \
  "s_sub_u32 s95, 0x7f, s93\n\t" \
  "s_add_u32 %[EA], %[EA], s95\n\t" \
  "v_mul_f32 v112, s94, v112\n\t" \
  "v_mul_f32 v113, s94, v113\n\t" \
  "v_mul_f32 v114, s94, v114\n\t" \
  "v_mul_f32 v115, s94, v115\n\t" \
  "v_mul_f32 v116, s94, v116\n\t"

// Variadic indirection so K0..K3 bundles expand before param matching.
#define ST(...) ST_X(__VA_ARGS__)
// Uniform consumer step: wait bank issued 4 steps ago (9 newer reads),
// commit row t, reissue same bank for row t+4.
#define ST_X(B0,B1,B2,BP,ROFF,RBOFF) \
  "s_waitcnt lgkmcnt(9)\n\t" \
  CMT(BP,B2) \
  "ds_read_b32 " B0 ", v12 offset:" ROFF "\n\t" \
  "ds_read_b32 " B1 ", v13 offset:" ROFF "\n\t" \
  "ds_read_b32 " B2 ", v14 offset:" RBOFF "\n\t" \
  ALPHA

// bank bundles (k = t & 3): c1, c3, cb, (c1:c3) pair
#define K0 "v96","v97","v98","v[96:97]"
#define K1 "v100","v101","v102","v[100:101]"
#define K2 "v104","v105","v106","v[104:105]"
#define K3 "v108","v109","v110","v[108:109]"

// ---- producer macros ----
#define PF(SL) \
  "global_load_dwordx4 v[" SL "], v10, %[P]\n\t" \
  "v_add_u32 v10, 0x400, v10\n\t"
// steady write+replenish: 16 in flight -> uniform vmcnt(15)
#define PWL(SL,OFF) \
  "s_waitcnt vmcnt(15)\n\t" \
  "ds_write_b128 v11, v[" SL "] offset:" OFF "\n\t" \
  "global_load_dwordx4 v[" SL "], v10, %[P]\n\t" \
  "v_add_u32 v10, 0x400, v10\n\t"
// tail write (no replenish, descending vmcnt)
#define PW(VC,SL,OFF) \
  "s_waitcnt vmcnt(" VC ")\n\t" \
  "ds_write_b128 v11, v[" SL "] offset:" OFF "\n\t"
// drain writes, then barrier (writes visible to consumer past this point)
#define PBAR \
  "s_waitcnt lgkmcnt(0)\n\t" \
  "s_barrier\n\t"

__global__ __launch_bounds__(128) void ctc_alpha_kernel(
    const int*   __restrict__ y_true,   // (B, U) int32
    const float* __restrict__ y_pred,   // (B, T, C) f32 softmax probs
    float*       __restrict__ out,      // (B, 1) f32
    int B)
{
  __shared__ float4 ldsbuf[1024];       // 16 KB: 32-row x 512 B ring

  const int b = blockIdx.x;
  if (b >= B) return;
  const int tid  = threadIdx.x;
  const int lane = tid & 63;
  const int wid  = tid >> 6;
  const unsigned lds_off = (unsigned)(uintptr_t)(void*)ldsbuf;

  if (wid == 1) {
    // ---------------- producer wave ----------------
    const float* __restrict__ p = y_pred + (size_t)b * (T_DIM * C_DIM);
    const int gvoff  = lane * 16;
    const int wraddr = (int)lds_off + lane * 16;
    asm volatile(
      "s_mov_b32 m0, -1\n\t"
      "v_mov_b32 v10, %[GV]\n\t"
      "v_mov_b32 v11, %[WA]\n\t"
      // 16 prologue loads (chunks 0..15)
      PF("32:35") PF("36:39") PF("40:43") PF("44:47")
      PF("48:51") PF("52:55") PF("56:59") PF("60:63")
      PF("64:67") PF("68:71") PF("72:75") PF("76:79")
      PF("80:83") PF("84:87") PF("88:91") PF("92:95")
      // stage groups 0,1 (chunks 0..7), replenish with chunks 16..23
      PWL("32:35","0")    PWL("36:39","1024") PWL("40:43","2048") PWL("44:47","3072")
      PWL("48:51","4096") PWL("52:55","5120") PWL("56:59","6144") PWL("60:63","7168")
      PBAR                                   // P0: rows 0..15 visible
      // main loop: 30 iters x 4 groups (g=0..119); stage group g+2
      "s_mov_b32 s90, 30\n"
      "LP_%=:\n\t"
      PBAR PWL("64:67","8192")  PWL("68:71","9216")  PWL("72:75","10240") PWL("76:79","11264")
      PBAR PWL("80:83","12288") PWL("84:87","13312") PWL("88:91","14336") PWL("92:95","15360")
      PBAR PWL("32:35","0")     PWL("36:39","1024")  PWL("40:43","2048")  PWL("44:47","3072")
      PBAR PWL("48:51","4096")  PWL("52:55","5120")  PWL("56:59","6144")  PWL("60:63","7168")
      "s_sub_u32 s90, s90, 1\n\t"
      "s_cmp_lg_u32 s90, 0\n\t"
      "s_cbranch_scc1 LP_%=\n\t"
      // g=120,121: last loads (chunks 504..511)
      PBAR PWL("64:67","8192")  PWL("68:71","9216")  PWL("72:75","10240") PWL("76:79","11264")
      PBAR PWL("80:83","12288") PWL("84:87","13312") PWL("88:91","14336") PWL("92:95","15360")
      // g=122..125: write-only, vmcnt descending 15..0
      PBAR PW("15","32:35","0")     PW("14","36:39","1024")  PW("13","40:43","2048")  PW("12","44:47","3072")
      PBAR PW("11","48:51","4096")  PW("10","52:55","5120")  PW("9","56:59","6144")   PW("8","60:63","7168")
      PBAR PW("7","64:67","8192")   PW("6","68:71","9216")   PW("5","72:75","10240")  PW("4","76:79","11264")
      PBAR PW("3","80:83","12288")  PW("2","84:87","13312")  PW("1","88:91","14336")  PW("0","92:95","15360")
      // g=126,127: bare barriers
      PBAR
      PBAR
      :
      : [P]"s"(p), [GV]"v"(gvoff), [WA]"v"(wraddr)
      : "v10","v11",
        "v32","v33","v34","v35","v36","v37","v38","v39","v40","v41","v42","v43",
        "v44","v45","v46","v47","v48","v49","v50","v51","v52","v53","v54","v55",
        "v56","v57","v58","v59","v60","v61","v62","v63","v64","v65","v66","v67",
        "v68","v69","v70","v71","v72","v73","v74","v75","v76","v77","v78","v79",
        "v80","v81","v82","v83","v84","v85","v86","v87","v88","v89","v90","v91",
        "v92","v93","v94","v95",
        "s90","scc","memory");
    return;
  }

  // ---------------- consumer wave ----------------
  const int* __restrict__ yb = y_true + b * U_DIM;
  const int blank = C_DIM - 1;
  const int ylab0 = yb[2 * lane];
  const int ylab1 = yb[2 * lane + 1];
  int yprev = blank;
  if (lane > 0) yprev = yb[2 * lane - 1];
  const float allow1 = (lane > 0 && ylab0 != blank && ylab0 != yprev) ? 1.0f : 0.0f;
  const float allow3 = (ylab1 != blank && ylab1 != ylab0)             ? 1.0f : 0.0f;

  const int rd1 = (int)lds_off + ylab0 * 4;    // gather addr, label0
  const int rd3 = (int)lds_off + ylab1 * 4;    // gather addr, label1
  const int rdb = (int)lds_off;                // row base (blank at +508)

  const float init0 = (lane == 0) ? 1.0f : 0.0f;
  float a3out, a4out;
  int   e_acc = 0;

  asm volatile(
    "s_mov_b32 m0, -1\n\t"
    "v_mov_b32 v12, %[R1]\n\t"
    "v_mov_b32 v13, %[R3]\n\t"
    "v_mov_b32 v14, %[RB]\n\t"
    "v_mov_b32 v30, %[L1]\n\t"
    "v_mov_b32 v31, %[L3]\n\t"
    "v_mov_b32 v112, %[I0]\n\t"
    "v_mov_b32 v113, 0\n\t"
    "v_mov_b32 v114, 0\n\t"
    "v_mov_b32 v115, 0\n\t"
    "v_mov_b32 v116, 0\n\t"
    "v_mov_b32 v124, " EPS_LIT "\n\t"
    "v_mov_b32 v125, " EPS_LIT "\n\t"
    "s_barrier\n\t"                          // P0: rows 0..15 staged
    // prime gathers for rows 0..3 into banks K0..K3 (12 reads)
    "ds_read_b32 v96, v12 offset:0\n\t"
    "ds_read_b32 v97, v13 offset:0\n\t"
    "ds_read_b32 v98, v14 offset:508\n\t"
    "ds_read_b32 v100, v12 offset:512\n\t"
    "ds_read_b32 v101, v13 offset:512\n\t"
    "ds_read_b32 v102, v14 offset:1020\n\t"
    "ds_read_b32 v104, v12 offset:1024\n\t"
    "ds_read_b32 v105, v13 offset:1024\n\t"
    "ds_read_b32 v106, v14 offset:1532\n\t"
    "ds_read_b32 v108, v12 offset:1536\n\t"
    "ds_read_b32 v109, v13 offset:1536\n\t"
    "ds_read_b32 v110, v14 offset:2044\n\t"
    // main loop: 32 iters x 32 steps; barrier per 8-row group
    "s_mov_b32 s90, 32\n"
    "LM_%=:\n\t"
    "s_barrier\n\t"
    ST(K0,"2048","2556")   ST(K1,"2560","3068")   ST(K2,"3072","3580")   ST(K3,"3584","4092")
    ST(K0,"4096","4604")   ST(K1,"4608","5116")   ST(K2,"5120","5628")   ST(K3,"5632","6140")
    RENORM
    "s_barrier\n\t"
    ST(K0,"6144","6652")   ST(K1,"6656","7164")   ST(K2,"7168","7676")   ST(K3,"7680","8188")
    ST(K0,"8192","8700")   ST(K1,"8704","9212")   ST(K2,"9216","9724")   ST(K3,"9728","10236")
    RENORM
    "s_barrier\n\t"
    ST(K0,"10240","10748") ST(K1,"10752","11260") ST(K2,"11264","11772") ST(K3,"11776","12284")
    ST(K0,"12288","12796") ST(K1,"12800","13308") ST(K2,"13312","13820") ST(K3,"13824","14332")
    RENORM
    "s_barrier\n\t"
    ST(K0,"14336","14844") ST(K1,"14848","15356") ST(K2,"15360","15868") ST(K3,"15872","16380")
    ST(K0,"0","508")       ST(K1,"512","1020")    ST(K2,"1024","1532")   ST(K3,"1536","2044")
    RENORM
    "s_sub_u32 s90, s90, 1\n\t"
    "s_cmp_lg_u32 s90, 0\n\t"
    "s_cbranch_scc1 LM_%=\n\t"
    "s_waitcnt lgkmcnt(0)\n\t"
    "v_mov_b32 %[O3], v115\n\t"
    "v_mov_b32 %[O4], v116\n\t"
    : [O3]"=v"(a3out), [O4]"=v"(a4out), [EA]"+s"(e_acc)
    : [R1]"v"(rd1), [R3]"v"(rd3), [RB]"v"(rdb),
      [L1]"v"(allow1), [L3]"v"(allow3), [I0]"v"(init0)
    : "v12","v13","v14","v30","v31",
      "v96","v97","v98","v100","v101","v102",
      "v104","v105","v106","v108","v109","v110",
      "v112","v113","v114","v115","v116","v117","v118","v119","v120","v121",
      "v122","v123","v124","v125","v126","v127",
      "s90","s91","s92","s93","s94","s95","scc","memory");

  if (lane == 63) {
    float s = a3out + a4out;           // alpha[255] + alpha[256]
    s = fmaxf(s, 1e-37f);
    float ll = logf(s) + (float)e_acc * LN2F;
    out[b] = -ll;
  }
}

extern "C" void kernel_launch(void* const* d_in, const int* in_sizes, int n_in,
                              void* d_out, int out_size, void* d_ws, size_t ws_size,
                              hipStream_t stream) {
  const int*   y_true = (const int*)d_in[0];
  const float* y_pred = (const float*)d_in[1];
  float*       out    = (float*)d_out;
  const int B = in_sizes[0] / U_DIM;   // 256
  ctc_alpha_kernel<<<dim3(B), dim3(128), 0, stream>>>(y_true, y_pred, out, B);
}